// Round 8
// baseline (1043.842 us; speedup 1.0000x reference)
//
#include <hip/hip_runtime.h>
#include <hip/hip_bf16.h>

// ---------------------------------------------------------------------------
// SemanticActor fused forward, bf16 MFMA (gfx950) — Round 16
// Register model (5 data points, R8-R15): launch_bounds 2nd arg = min
// waves/EU; caps TOTAL arch+acc at 512/waves, split chosen by compiler.
// Spills match WRITE_SIZE in every round. This family is pinned at 8
// waves/CU in ONE barrier domain -> ~13 full-CU barrier drains are the
// structural 2.7x gap to the 43us MFMA floor.
// R16: delete the barriers. Each wave owns 16 batch rows END-TO-END:
// GEMM2/3/4's K (256 h-cols) becomes wave-local; the H exchange is a
// register lane-permute (cvt_pk + ds_bpermute + cndmask), not an LDS
// round-trip. W2 staged once in LDS (128KB, read barrier-free); W1P/W3/W4
// streamed from L2/L1 (8 waves co-read -> L1 broadcast); raw B-frags in 16
// regs. 3 barriers total, ZERO in the main loop. Peak regs ~216 <= 256
// under (512,2) -> 2 waves/SIMD, no spill.
// Permute (from m89 layouts): dest(q,l15) dword m <- src((q&1)*2+(m>>1),
// l15), tile 2ks+(q>>1), word m&1.  Predict: conflicts <1M, MfmaUtil 45-60,
// dur 60-80us. If W1P streaming binds: ~90us, fix = LDS-stage W1P per pair.
// ---------------------------------------------------------------------------

#define B_TOTAL 65536
#define TROWS   128
#define RSTR    136   // rawS row stride elems (272B) -> 2-way-ish on reads

typedef __attribute__((ext_vector_type(8))) short s8v;   // 8 x bf16
typedef __attribute__((ext_vector_type(4))) float f4v;   // MFMA C/D

__constant__ int c_PI[6] = {0,0,1,1,2,2};
__constant__ int c_PJ[6] = {1,2,0,2,0,1};
__constant__ int c_PF[6] = {0,0,1,0,1,1};
// inverse of FIRST_INDS / SECOND_INDS: raw ag/g col -> X col (or -1)
__constant__ int c_INV[2][30] = {
  {0,1,2,3,4,5,6,7,8,9,10,11,12,13,-1,14,15,16,-1,-1,17,18,-1,-1,-1,19,-1,-1,-1,-1},
  {0,1,2,3,4,5,6,7,8,9,-1,-1,-1,-1,10,-1,-1,-1,11,12,-1,-1,13,14,15,-1,16,17,18,19}};

static __device__ __forceinline__ short bf16s(float v) {
  __hip_bfloat16 h = __float2bfloat16(v);
  union { __hip_bfloat16 h; short s; } u; u.h = h; return u.s;
}

// ---- prep: one 512-elem fragment per wave (UNCHANGED from R10) -------------
__global__ __launch_bounds__(256)
void prep_weights(const float* __restrict__ phi_w1,
                  const float* __restrict__ phi_b1,
                  const float* __restrict__ phi_w2,
                  const float* __restrict__ rho_w1,
                  const float* __restrict__ mean_w,
                  const float* __restrict__ logstd_w,
                  __hip_bfloat16* __restrict__ W1P,
                  __hip_bfloat16* __restrict__ W2f,
                  __hip_bfloat16* __restrict__ W3f,
                  __hip_bfloat16* __restrict__ W4f) {
  const int wid  = (blockIdx.x * blockDim.x + threadIdx.x) >> 6;
  const int lane = threadIdx.x & 63;
  const int l15  = lane & 15;
  const int kq   = (lane >> 4) * 8;
  if (wid >= 648) return;
  union { short s[8]; s8v v; } o;
  __hip_bfloat16* dst;
  if (wid < 384) {
    const int p = wid >> 6, rem = wid & 63;
    const int nb = rem >> 2, ks = rem & 3;
    const int n = nb * 16 + l15;
    const int f = c_PF[p], oi = c_PI[p], oj = c_PJ[p];
#pragma unroll
    for (int j = 0; j < 8; ++j) {
      int k = ks * 32 + kq + j;
      float v = 0.0f;
      if (k < 30)       { int t = c_INV[f][k];      if (t >= 0) v = phi_w1[t * 256 + n]; }
      else if (k < 60)  { int t = c_INV[f][k - 30]; if (t >= 0) v = phi_w1[(30 + t) * 256 + n]; }
      else if (k < 70)  { v = phi_w1[(20 + k - 60) * 256 + n]; }
      else if (k < 115) { int q = (k - 70) / 15, t = (k - 70) - q * 15;
                          int c = (q == oi) ? 50 + t : (q == oj) ? 65 + t : -1;
                          if (c >= 0) v = phi_w1[c * 256 + n]; }
      else if (k == 115) v = phi_b1[n];   // bias via ones-column
      o.s[j] = bf16s(v);
    }
    dst = W1P + wid * 512 + lane * 8;
  } else if (wid < 512) {
    const int r = wid - 384;
    const int nb = r >> 3, ks = r & 7;
    const int n = nb * 16 + l15;
#pragma unroll
    for (int j = 0; j < 8; ++j)
      o.s[j] = bf16s(phi_w2[(ks * 32 + kq + j) * 256 + n]);
    dst = W2f + r * 512 + lane * 8;
  } else if (wid < 640) {
    const int r = wid - 512;
    const int nb = r >> 3, ks = r & 7;
    const int n = nb * 16 + l15;
#pragma unroll
    for (int j = 0; j < 8; ++j)
      o.s[j] = bf16s(rho_w1[(ks * 32 + kq + j) * 256 + n]);
    dst = W3f + r * 512 + lane * 8;
  } else {
    const int ks = wid - 640;
    const int n = l15;
#pragma unroll
    for (int j = 0; j < 8; ++j) {
      int k = ks * 32 + kq + j;
      float v = (n < 4) ? mean_w[k * 4 + n]
              : (n < 8) ? logstd_w[k * 4 + (n - 4)] : 0.0f;
      o.s[j] = bf16s(v);
    }
    dst = W4f + ks * 512 + lane * 8;
  }
  *reinterpret_cast<s8v*>(dst) = o.v;
}

static __device__ __forceinline__ unsigned pk2(float a, float b) {
  __hip_bfloat162 h = __float22bfloat162_rn(float2{a, b});
  union { __hip_bfloat162 h2; unsigned u; } cv; cv.h2 = h;
  return cv.u;
}

// lane-permute: 16 tiles of packed (pkA=cols 0-1, pkB=cols 2-3) -> 8 K-slice
// B-frags. dest(q,l15) dword m <- src((q&1)*2+(m>>1), l15) tile 2ks+(q>>1)
// word m&1.
static __device__ __forceinline__ void xshuffle(const int* pkA, const int* pkB,
                                                s8v* bf, int idxA, int idxB,
                                                bool hi) {
#pragma unroll
  for (int ks = 0; ks < 8; ++ks) {
    int a0 = __builtin_amdgcn_ds_bpermute(idxA, pkA[2 * ks]);
    int b0 = __builtin_amdgcn_ds_bpermute(idxA, pkA[2 * ks + 1]);
    int a1 = __builtin_amdgcn_ds_bpermute(idxA, pkB[2 * ks]);
    int b1 = __builtin_amdgcn_ds_bpermute(idxA, pkB[2 * ks + 1]);
    int a2 = __builtin_amdgcn_ds_bpermute(idxB, pkA[2 * ks]);
    int b2 = __builtin_amdgcn_ds_bpermute(idxB, pkA[2 * ks + 1]);
    int a3 = __builtin_amdgcn_ds_bpermute(idxB, pkB[2 * ks]);
    int b3 = __builtin_amdgcn_ds_bpermute(idxB, pkB[2 * ks + 1]);
    union { int i[4]; s8v v; } u;
    u.i[0] = hi ? b0 : a0;
    u.i[1] = hi ? b1 : a1;
    u.i[2] = hi ? b2 : a2;
    u.i[3] = hi ? b3 : a3;
    bf[ks] = u.v;
  }
}

// ---- main: 512 thr (8 waves), 128 rows/block, wave owns 16 rows end-to-end
__global__ __launch_bounds__(512, 2)
void actor_main(const float* __restrict__ obs, const float* __restrict__ ag,
                const float* __restrict__ g,
                const __hip_bfloat16* __restrict__ W1P,
                const __hip_bfloat16* __restrict__ W2f,
                const __hip_bfloat16* __restrict__ W3f,
                const __hip_bfloat16* __restrict__ W4f,
                const float* __restrict__ b2, const float* __restrict__ b3,
                const float* __restrict__ meanb,
                const float* __restrict__ logstdb,
                float* __restrict__ out) {
  // phase 1: lds[0..34816) = rawS (128 rows x 136 elems)
  // phase 2: lds[0..131072) = W2 staged; [131072..133120) = b2s|b3s (f32)
  __shared__ __align__(16) char ldsbuf[133120];
  __hip_bfloat16* rawS = (__hip_bfloat16*)ldsbuf;
  __hip_bfloat16* w2s  = (__hip_bfloat16*)ldsbuf;
  float* b2s = (float*)(ldsbuf + 131072);
  float* b3s = (float*)(ldsbuf + 131072 + 1024);

  const int tid  = threadIdx.x;
  const int lane = tid & 63;
  const int w    = tid >> 6;        // wave 0..7 -> batch rows [16w, 16w+16)
  const int l15  = lane & 15;
  const int quad = lane >> 4;
  const int q4   = quad * 4;
  const bool hi  = lane >= 32;      // q>>1
  const int r0   = blockIdx.x * TROWS;
  const int fbase = lane * 8;       // elem offset within a 512-elem frag

  // bpermute byte indices: src lane = ((q&1)*2 + (m>>1))*16 + l15
  const int idxA = (((quad & 1) * 2) * 16 + l15) * 4;
  const int idxB = idxA + 64;

  // ---- phase 1: stage raw [ag|g|obs|1|0] bf16, 128 rows x 128 cols --------
  {
    const int row = tid >> 2;           // 0..127
    const int c0  = (tid & 3) * 32;     // 0,32,64,96
    const float* agr = ag  + (size_t)(r0 + row) * 30;
    const float* gr  = g   + (size_t)(r0 + row) * 30;
    const float* obr = obs + (size_t)(r0 + row) * 55;
    union { short s[32]; s8v v[4]; } o;
#pragma unroll
    for (int cc = 0; cc < 32; ++cc) {
      int c = c0 + cc;
      float v;
      if      (c < 30)  v = agr[c];
      else if (c < 60)  v = gr[c - 30];
      else if (c < 115) v = obr[c - 60];
      else if (c == 115) v = 1.0f;
      else              v = 0.0f;
      o.s[cc] = bf16s(v);
    }
#pragma unroll
    for (int k = 0; k < 4; ++k)
      *reinterpret_cast<s8v*>(&rawS[row * RSTR + c0 + k * 8]) = o.v[k];
    // biases -> LDS (region disjoint from rawS)
    if (tid < 256)      b2s[tid] = b2[tid];
    else                b3s[tid - 256] = b3[tid - 256];
  }
  __syncthreads();   // raw staged

  // ---- raw B-frags -> registers (one-time) --------------------------------
  s8v rawf[4];
#pragma unroll
  for (int ks = 0; ks < 4; ++ks)
    rawf[ks] = *(const s8v*)&rawS[(w * 16 + l15) * RSTR + ks * 32 + quad * 8];
  __syncthreads();   // all waves done reading raw area

  // ---- phase 2: stage W2 (128KB) into same LDS ----------------------------
#pragma unroll
  for (int it = 0; it < 16; ++it)
    *reinterpret_cast<s8v*>(&w2s[(it * 512 + tid) * 8]) =
        *(const s8v*)&W2f[(size_t)(it * 512 + tid) * 8];
  __syncthreads();   // W2 visible — LAST barrier; loop below is barrier-free

  f4v agg[16];
#pragma unroll
  for (int t = 0; t < 16; ++t) agg[t] = f4v{0.f, 0.f, 0.f, 0.f};

#pragma unroll 1
  for (int p = 0; p < 6; ++p) {
    const __hip_bfloat16* w1base = W1P + p * 32768;

    // GEMM1: h = W1P[p](A) x raw(B); wave's 16 rows x all 256 h-cols.
    // A streamed from L2/L1 (8 waves co-read -> L1 broadcast), B in regs.
    f4v h[16];
#pragma unroll
    for (int t = 0; t < 16; ++t) h[t] = f4v{0.f, 0.f, 0.f, 0.f};
#pragma unroll
    for (int nb = 0; nb < 16; ++nb)
#pragma unroll
      for (int ks = 0; ks < 4; ++ks) {
        s8v w1a = *(const s8v*)&w1base[(nb * 4 + ks) * 512 + fbase];
        h[nb] = __builtin_amdgcn_mfma_f32_16x16x32_bf16(w1a, rawf[ks], h[nb], 0, 0, 0);
      }

    // pack relu(h) -> bf16 word pairs (bias b1 folded via ones-column)
    int pkA[16], pkB[16];
#pragma unroll
    for (int t = 0; t < 16; ++t) {
      pkA[t] = pk2(fmaxf(h[t][0], 0.f), fmaxf(h[t][1], 0.f));
      pkB[t] = pk2(fmaxf(h[t][2], 0.f), fmaxf(h[t][3], 0.f));
    }
    // lane-permute -> 8 K-slice B-frags (register-only, no barrier)
    s8v bf[8];
    xshuffle(pkA, pkB, bf, idxA, idxB, hi);

    // GEMM2: a2 = W2(A from LDS) x H(B in regs); agg += relu(a2 + b2)
#pragma unroll
    for (int nb = 0; nb < 16; ++nb) {
      f4v a2 = f4v{0.f, 0.f, 0.f, 0.f};
#pragma unroll
      for (int ks = 0; ks < 8; ++ks) {
        s8v w2a = *(const s8v*)&w2s[(nb * 8 + ks) * 512 + fbase];
        a2 = __builtin_amdgcn_mfma_f32_16x16x32_bf16(w2a, bf[ks], a2, 0, 0, 0);
      }
      float4 bb = *(const float4*)&b2s[nb * 16 + q4];  // broadcast read
      agg[nb][0] += fmaxf(a2[0] + bb.x, 0.f);
      agg[nb][1] += fmaxf(a2[1] + bb.y, 0.f);
      agg[nb][2] += fmaxf(a2[2] + bb.z, 0.f);
      agg[nb][3] += fmaxf(a2[3] + bb.w, 0.f);
    }
  }

  // ---- GEMM3: hr = relu(W3 x agg + b3); agg already >= 0, pack direct -----
  {
    int pkA[16], pkB[16];
#pragma unroll
    for (int t = 0; t < 16; ++t) {
      pkA[t] = pk2(agg[t][0], agg[t][1]);
      pkB[t] = pk2(agg[t][2], agg[t][3]);
    }
    s8v af[8];
    xshuffle(pkA, pkB, af, idxA, idxB, hi);

    f4v a3[16];
#pragma unroll
    for (int t = 0; t < 16; ++t) a3[t] = f4v{0.f, 0.f, 0.f, 0.f};
#pragma unroll
    for (int nb = 0; nb < 16; ++nb)
#pragma unroll
      for (int ks = 0; ks < 8; ++ks) {
        s8v w3a = *(const s8v*)&W3f[(nb * 8 + ks) * 512 + fbase];
        a3[nb] = __builtin_amdgcn_mfma_f32_16x16x32_bf16(w3a, af[ks], a3[nb], 0, 0, 0);
      }

    // pack relu(a3 + b3) -> B-frags for heads
#pragma unroll
    for (int t = 0; t < 16; ++t) {
      float4 bb = *(const float4*)&b3s[t * 16 + q4];
      pkA[t] = pk2(fmaxf(a3[t][0] + bb.x, 0.f), fmaxf(a3[t][1] + bb.y, 0.f));
      pkB[t] = pk2(fmaxf(a3[t][2] + bb.z, 0.f), fmaxf(a3[t][3] + bb.w, 0.f));
    }
    s8v hf[8];
    xshuffle(pkA, pkB, hf, idxA, idxB, hi);

    // GEMM4: heads (8 real cols of 16); A streamed, B in regs
    f4v a4 = f4v{0.f, 0.f, 0.f, 0.f};
#pragma unroll
    for (int ks = 0; ks < 8; ++ks) {
      s8v w4 = *(const s8v*)&W4f[ks * 512 + fbase];
      a4 = __builtin_amdgcn_mfma_f32_16x16x32_bf16(w4, hf[ks], a4, 0, 0, 0);
    }
    // D: row(M)=quad*4+r = head col, col(N)=l15 = batch row
    const int row = r0 + w * 16 + l15;
    if (quad == 0) {          // head cols 0..3 = mean
      float4 mb = *(const float4*)meanb;
      float4 o;
      o.x = a4[0] + mb.x; o.y = a4[1] + mb.y;
      o.z = a4[2] + mb.z; o.w = a4[3] + mb.w;
      *reinterpret_cast<float4*>(&out[(size_t)row * 4]) = o;
    } else if (quad == 1) {   // head cols 4..7 = logstd (clipped)
      float4 lb = *(const float4*)logstdb;
      float4 o;
      o.x = fminf(fmaxf(a4[0] + lb.x, -20.f), 2.f);
      o.y = fminf(fmaxf(a4[1] + lb.y, -20.f), 2.f);
      o.z = fminf(fmaxf(a4[2] + lb.z, -20.f), 2.f);
      o.w = fminf(fmaxf(a4[3] + lb.w, -20.f), 2.f);
      *reinterpret_cast<float4*>(&out[(size_t)B_TOTAL * 4 + (size_t)row * 4]) = o;
    }
  }
}

extern "C" void kernel_launch(void* const* d_in, const int* in_sizes, int n_in,
                              void* d_out, int out_size, void* d_ws, size_t ws_size,
                              hipStream_t stream) {
  const float* obs      = (const float*)d_in[0];
  const float* ag       = (const float*)d_in[1];
  const float* g        = (const float*)d_in[2];
  const float* phi_w1   = (const float*)d_in[3];
  const float* phi_b1   = (const float*)d_in[4];
  const float* phi_w2   = (const float*)d_in[5];
  const float* phi_b2   = (const float*)d_in[6];
  const float* rho_w1   = (const float*)d_in[7];
  const float* rho_b1   = (const float*)d_in[8];
  const float* mean_w   = (const float*)d_in[9];
  const float* mean_b   = (const float*)d_in[10];
  const float* logstd_w = (const float*)d_in[11];
  const float* logstd_b = (const float*)d_in[12];
  float* out = (float*)d_out;

  // ws (bf16): W1P 6x32768 | W2f 65536 | W3f 65536 | W4f 4096 elems
  char* ws = (char*)d_ws;
  __hip_bfloat16* W1P = (__hip_bfloat16*)(ws);
  __hip_bfloat16* W2f = (__hip_bfloat16*)(ws + 393216);
  __hip_bfloat16* W3f = (__hip_bfloat16*)(ws + 393216 + 131072);
  __hip_bfloat16* W4f = (__hip_bfloat16*)(ws + 393216 + 262144);

  prep_weights<<<162, 256, 0, stream>>>(phi_w1, phi_b1, phi_w2, rho_w1,
                                        mean_w, logstd_w, W1P, W2f, W3f, W4f);
  actor_main<<<B_TOTAL / TROWS, 512, 0, stream>>>(
      obs, ag, g, W1P, W2f, W3f, W4f, phi_b2, rho_b1, mean_b, logstd_b, out);
}

// Round 9
// 189.860 us; speedup vs baseline: 5.4979x; 5.4979x over previous
//
#include <hip/hip_runtime.h>
#include <hip/hip_bf16.h>

// ---------------------------------------------------------------------------
// SemanticActor fused forward, bf16 MFMA (gfx950) — Round 17 (= R8 restore)
// Final model (6 data points, R8-R16): the unified VGPR+AGPR file pins every
// viable geometry at ~230-260 regs/wave -> 2 waves/SIMD -> 8 waves/CU, one
// barrier domain. All residency-breaking attempts spilled (spill count ==
// WRITE_SIZE each round). Barriers measured ~free (R8 2/pair == R10 3/pair,
// 116.6 vs 117.1us). H-operand LDS duplication is coverage-fixed; register
// geometries that avoid it (R16) exceed the file and spill 5-10x worse.
// R8 is the empirical optimum of this family: double-buffered HsBuf,
// persistent w2f, W1P register prefetch, (512,2). Restored verbatim.
// ---------------------------------------------------------------------------

#define B_TOTAL 65536
#define TROWS   64
#define RSTR    136   // rawS row stride elems: 272B = 17x16B -> optimal b128 phasing

typedef __attribute__((ext_vector_type(8))) short s8v;   // 8 x bf16
typedef __attribute__((ext_vector_type(4))) float f4v;   // MFMA C/D

__constant__ int c_PI[6] = {0,0,1,1,2,2};
__constant__ int c_PJ[6] = {1,2,0,2,0,1};
__constant__ int c_PF[6] = {0,0,1,0,1,1};
// inverse of FIRST_INDS / SECOND_INDS: raw ag/g col -> X col (or -1)
__constant__ int c_INV[2][30] = {
  {0,1,2,3,4,5,6,7,8,9,10,11,12,13,-1,14,15,16,-1,-1,17,18,-1,-1,-1,19,-1,-1,-1,-1},
  {0,1,2,3,4,5,6,7,8,9,-1,-1,-1,-1,10,-1,-1,-1,11,12,-1,-1,13,14,15,-1,16,17,18,19}};

static __device__ __forceinline__ short bf16s(float v) {
  __hip_bfloat16 h = __float2bfloat16(v);
  union { __hip_bfloat16 h; short s; } u; u.h = h; return u.s;
}

// ---- prep: one 512-elem fragment per wave; coalesced reads, b128 writes ----
// tasks: [0,384) W1P (p=wid>>6, nb=rem>>2, ks=rem&3) | [384,512) W2f |
//        [512,640) W3f | [640,648) W4f
__global__ __launch_bounds__(256)
void prep_weights(const float* __restrict__ phi_w1,
                  const float* __restrict__ phi_b1,
                  const float* __restrict__ phi_w2,
                  const float* __restrict__ rho_w1,
                  const float* __restrict__ mean_w,
                  const float* __restrict__ logstd_w,
                  __hip_bfloat16* __restrict__ W1P,
                  __hip_bfloat16* __restrict__ W2f,
                  __hip_bfloat16* __restrict__ W3f,
                  __hip_bfloat16* __restrict__ W4f) {
  const int wid  = (blockIdx.x * blockDim.x + threadIdx.x) >> 6;
  const int lane = threadIdx.x & 63;
  const int l15  = lane & 15;
  const int kq   = (lane >> 4) * 8;
  if (wid >= 648) return;
  union { short s[8]; s8v v; } o;
  __hip_bfloat16* dst;
  if (wid < 384) {
    const int p = wid >> 6, rem = wid & 63;
    const int nb = rem >> 2, ks = rem & 3;
    const int n = nb * 16 + l15;
    const int f = c_PF[p], oi = c_PI[p], oj = c_PJ[p];
#pragma unroll
    for (int j = 0; j < 8; ++j) {
      int k = ks * 32 + kq + j;
      float v = 0.0f;
      if (k < 30)       { int t = c_INV[f][k];      if (t >= 0) v = phi_w1[t * 256 + n]; }
      else if (k < 60)  { int t = c_INV[f][k - 30]; if (t >= 0) v = phi_w1[(30 + t) * 256 + n]; }
      else if (k < 70)  { v = phi_w1[(20 + k - 60) * 256 + n]; }
      else if (k < 115) { int q = (k - 70) / 15, t = (k - 70) - q * 15;
                          int c = (q == oi) ? 50 + t : (q == oj) ? 65 + t : -1;
                          if (c >= 0) v = phi_w1[c * 256 + n]; }
      else if (k == 115) v = phi_b1[n];   // bias via ones-column
      o.s[j] = bf16s(v);
    }
    dst = W1P + wid * 512 + lane * 8;
  } else if (wid < 512) {
    const int r = wid - 384;
    const int nb = r >> 3, ks = r & 7;
    const int n = nb * 16 + l15;
#pragma unroll
    for (int j = 0; j < 8; ++j)
      o.s[j] = bf16s(phi_w2[(ks * 32 + kq + j) * 256 + n]);
    dst = W2f + r * 512 + lane * 8;
  } else if (wid < 640) {
    const int r = wid - 512;
    const int nb = r >> 3, ks = r & 7;
    const int n = nb * 16 + l15;
#pragma unroll
    for (int j = 0; j < 8; ++j)
      o.s[j] = bf16s(rho_w1[(ks * 32 + kq + j) * 256 + n]);
    dst = W3f + r * 512 + lane * 8;
  } else {
    const int ks = wid - 640;
    const int n = l15;
#pragma unroll
    for (int j = 0; j < 8; ++j) {
      int k = ks * 32 + kq + j;
      float v = (n < 4) ? mean_w[k * 4 + n]
              : (n < 8) ? logstd_w[k * 4 + (n - 4)] : 0.0f;
      o.s[j] = bf16s(v);
    }
    dst = W4f + ks * 512 + lane * 8;
  }
  *reinterpret_cast<s8v*>(dst) = o.v;
}

static __device__ __forceinline__ unsigned pk2(float a, float b) {
  __hip_bfloat162 h = __float22bfloat162_rn(float2{a, b});
  union { __hip_bfloat162 h2; unsigned u; } cv; cv.h2 = h;
  return cv.u;
}

// ---- main: 512 threads (8 waves), 64 rows/block, wave = 32-col slice -------
__global__ __launch_bounds__(512, 2)
void actor_main(const float* __restrict__ obs, const float* __restrict__ ag,
                const float* __restrict__ g,
                const __hip_bfloat16* __restrict__ W1P,
                const __hip_bfloat16* __restrict__ W2f,
                const __hip_bfloat16* __restrict__ W3f,
                const __hip_bfloat16* __restrict__ W4f,
                const float* __restrict__ b2, const float* __restrict__ b3,
                const float* __restrict__ meanb,
                const float* __restrict__ logstdb,
                float* __restrict__ out) {
  __shared__ __align__(16) __hip_bfloat16 rawS[TROWS * RSTR];      // 34 KB
  __shared__ __align__(16) __hip_bfloat16 HsBuf[2][4 * 8 * 512];   // 64 KB

  const int tid  = threadIdx.x;
  const int lane = tid & 63;
  const int w    = tid >> 6;      // wave 0..7 -> hidden cols [32w, 32w+32)
  const int l15  = lane & 15;
  const int quad = lane >> 4;
  const int r0   = blockIdx.x * TROWS;

  float4 b2v[2];
#pragma unroll
  for (int i = 0; i < 2; ++i)
    b2v[i] = *(const float4*)&b2[w * 32 + i * 16 + quad * 4];

  // persistent W2 fragments (once per block)
  s8v w2f[8][2];
#pragma unroll
  for (int i = 0; i < 2; ++i)
#pragma unroll
    for (int ks = 0; ks < 8; ++ks)
      w2f[ks][i] = *(const s8v*)&W2f[(((w * 2 + i) * 8 + ks) * 512) + lane * 8];

  // stage raw input [ag|g|obs|1|0] bf16 K=128 (vectorized: 2 b128 stores/thread)
  {
    const int row = tid >> 3;           // 0..63
    const int c0  = (tid & 7) * 16;     // 0..112
    const float* agr = ag  + (size_t)(r0 + row) * 30;
    const float* gr  = g   + (size_t)(r0 + row) * 30;
    const float* obr = obs + (size_t)(r0 + row) * 55;
    union { short s[16]; s8v v[2]; } o;
#pragma unroll
    for (int cc = 0; cc < 16; ++cc) {
      int c = c0 + cc;
      float v;
      if      (c < 30)  v = agr[c];
      else if (c < 60)  v = gr[c - 30];
      else if (c < 115) v = obr[c - 60];
      else if (c == 115) v = 1.0f;
      else              v = 0.0f;
      o.s[cc] = bf16s(v);
    }
    *reinterpret_cast<s8v*>(&rawS[row * RSTR + c0])     = o.v[0];
    *reinterpret_cast<s8v*>(&rawS[row * RSTR + c0 + 8]) = o.v[1];
  }

  // preload pair 0's W1P frags
  s8v w1c[4][2], w1n[4][2];
#pragma unroll
  for (int i = 0; i < 2; ++i)
#pragma unroll
    for (int ks = 0; ks < 4; ++ks)
      w1c[ks][i] = *(const s8v*)&W1P[(((w * 2 + i) * 4 + ks) * 512) + lane * 8];

  f4v agg[2][4];
#pragma unroll
  for (int i = 0; i < 2; ++i)
#pragma unroll
    for (int rt = 0; rt < 4; ++rt) agg[i][rt] = f4v{0.f, 0.f, 0.f, 0.f};

  const int ebase = l15 * 8 + (quad >> 1) * 128 + (quad & 1) * 4;

  __syncthreads();  // rawS staged

#pragma unroll 1
  for (int p = 0; p < 6; ++p) {
    __hip_bfloat16* buf = &HsBuf[p & 1][0];

    // prefetch NEXT pair's W1P frags early (consumed only after GEMM2+copy:
    // latency hidden under GEMM1 MFMAs + barrier + GEMM2)
    if (p < 5) {
      const __hip_bfloat16* nb = W1P + (p + 1) * 32768;
#pragma unroll
      for (int i = 0; i < 2; ++i)
#pragma unroll
        for (int ks = 0; ks < 4; ++ks)
          w1n[ks][i] = *(const s8v*)&nb[(((w * 2 + i) * 4 + ks) * 512) + lane * 8];
    }

    // GEMM1: h = W1P[p](A) x raw(B); K=128; raw B-frags from LDS
    f4v h[2][4];
#pragma unroll
    for (int i = 0; i < 2; ++i)
#pragma unroll
      for (int rt = 0; rt < 4; ++rt) h[i][rt] = f4v{0.f, 0.f, 0.f, 0.f};
#pragma unroll
    for (int ks = 0; ks < 4; ++ks) {
      s8v bx[4];
#pragma unroll
      for (int rt = 0; rt < 4; ++rt)
        bx[rt] = *(const s8v*)&rawS[(rt * 16 + l15) * RSTR + ks * 32 + quad * 8];
#pragma unroll
      for (int i = 0; i < 2; ++i)
#pragma unroll
        for (int rt = 0; rt < 4; ++rt)
          h[i][rt] = __builtin_amdgcn_mfma_f32_16x16x32_bf16(w1c[ks][i], bx[rt], h[i][rt], 0, 0, 0);
    }
    // epilogue: relu (bias folded via ones-column), pack -> b64 writes
#pragma unroll
    for (int i = 0; i < 2; ++i)
#pragma unroll
      for (int rt = 0; rt < 4; ++rt) {
        float v0 = fmaxf(h[i][rt][0], 0.f);
        float v1 = fmaxf(h[i][rt][1], 0.f);
        float v2 = fmaxf(h[i][rt][2], 0.f);
        float v3 = fmaxf(h[i][rt][3], 0.f);
        uint2 U; U.x = pk2(v0, v1); U.y = pk2(v2, v3);
        *reinterpret_cast<uint2*>(&buf[(rt * 8 + w) * 512 + i * 256 + ebase]) = U;
      }
    __syncthreads();  // H(p) complete; buf[(p+1)&1]'s old readers fenced by
                      // the previous iteration's barrier

    // GEMM2: a2 = W2(A) x H(B); K=256; agg += relu(a2 + b2)
    f4v a2[2][4];
#pragma unroll
    for (int i = 0; i < 2; ++i)
#pragma unroll
      for (int rt = 0; rt < 4; ++rt) a2[i][rt] = f4v{0.f, 0.f, 0.f, 0.f};
#pragma unroll
    for (int ks = 0; ks < 8; ++ks) {
      s8v hf[4];
#pragma unroll
      for (int rt = 0; rt < 4; ++rt)
        hf[rt] = *(const s8v*)&buf[(rt * 8 + ks) * 512 + lane * 8];
#pragma unroll
      for (int i = 0; i < 2; ++i)
#pragma unroll
        for (int rt = 0; rt < 4; ++rt)
          a2[i][rt] = __builtin_amdgcn_mfma_f32_16x16x32_bf16(w2f[ks][i], hf[rt], a2[i][rt], 0, 0, 0);
    }
#pragma unroll
    for (int i = 0; i < 2; ++i)
#pragma unroll
      for (int rt = 0; rt < 4; ++rt) {
        agg[i][rt][0] += fmaxf(a2[i][rt][0] + b2v[i].x, 0.f);
        agg[i][rt][1] += fmaxf(a2[i][rt][1] + b2v[i].y, 0.f);
        agg[i][rt][2] += fmaxf(a2[i][rt][2] + b2v[i].z, 0.f);
        agg[i][rt][3] += fmaxf(a2[i][rt][3] + b2v[i].w, 0.f);
      }

    // rotate prefetch buffer
    if (p < 5) {
#pragma unroll
      for (int i = 0; i < 2; ++i)
#pragma unroll
        for (int ks = 0; ks < 4; ++ks)
          w1c[ks][i] = w1n[ks][i];
    }
  }

  // W3 frags + b3 (late-loaded)
  s8v w3f[8][2];
#pragma unroll
  for (int i = 0; i < 2; ++i)
#pragma unroll
    for (int ks = 0; ks < 8; ++ks)
      w3f[ks][i] = *(const s8v*)&W3f[(((w * 2 + i) * 8 + ks) * 512) + lane * 8];
  float4 b3v[2];
#pragma unroll
  for (int i = 0; i < 2; ++i)
    b3v[i] = *(const float4*)&b3[w * 32 + i * 16 + quad * 4];

  // stash agg (bf16) into buf0, frag-major (buf0 readers fenced by p=5 barrier)
  {
    __hip_bfloat16* bufA = &HsBuf[0][0];
#pragma unroll
    for (int i = 0; i < 2; ++i)
#pragma unroll
      for (int rt = 0; rt < 4; ++rt) {
        uint2 U; U.x = pk2(agg[i][rt][0], agg[i][rt][1]);
        U.y = pk2(agg[i][rt][2], agg[i][rt][3]);
        *reinterpret_cast<uint2*>(&bufA[(rt * 8 + w) * 512 + i * 256 + ebase]) = U;
      }
  }
  __syncthreads();

  // GEMM3: hr = relu(W3(A) x agg(B) + b3); reads buf0, writes buf1
  f4v a3[2][4];
#pragma unroll
  for (int i = 0; i < 2; ++i)
#pragma unroll
    for (int rt = 0; rt < 4; ++rt) a3[i][rt] = f4v{0.f, 0.f, 0.f, 0.f};
  {
    const __hip_bfloat16* bufA = &HsBuf[0][0];
#pragma unroll
    for (int ks = 0; ks < 8; ++ks) {
      s8v hf[4];
#pragma unroll
      for (int rt = 0; rt < 4; ++rt)
        hf[rt] = *(const s8v*)&bufA[(rt * 8 + ks) * 512 + lane * 8];
#pragma unroll
      for (int i = 0; i < 2; ++i)
#pragma unroll
        for (int rt = 0; rt < 4; ++rt)
          a3[i][rt] = __builtin_amdgcn_mfma_f32_16x16x32_bf16(w3f[ks][i], hf[rt], a3[i][rt], 0, 0, 0);
    }
  }
  {
    __hip_bfloat16* bufB = &HsBuf[1][0];
#pragma unroll
    for (int i = 0; i < 2; ++i)
#pragma unroll
      for (int rt = 0; rt < 4; ++rt) {
        float v0 = fmaxf(a3[i][rt][0] + b3v[i].x, 0.f);
        float v1 = fmaxf(a3[i][rt][1] + b3v[i].y, 0.f);
        float v2 = fmaxf(a3[i][rt][2] + b3v[i].z, 0.f);
        float v3 = fmaxf(a3[i][rt][3] + b3v[i].w, 0.f);
        uint2 U; U.x = pk2(v0, v1); U.y = pk2(v2, v3);
        *reinterpret_cast<uint2*>(&bufB[(rt * 8 + w) * 512 + i * 256 + ebase]) = U;
      }
  }
  __syncthreads();

  // GEMM4: heads; waves 0..3 take batch tile rt=w; reads buf1
  if (w < 4) {
    const __hip_bfloat16* bufB = &HsBuf[1][0];
    f4v a4 = f4v{0.f, 0.f, 0.f, 0.f};
#pragma unroll
    for (int ks = 0; ks < 8; ++ks) {
      s8v w4 = *(const s8v*)&W4f[ks * 512 + lane * 8];
      s8v hf = *(const s8v*)&bufB[(w * 8 + ks) * 512 + lane * 8];
      a4 = __builtin_amdgcn_mfma_f32_16x16x32_bf16(w4, hf, a4, 0, 0, 0);
    }
    const int row = r0 + w * 16 + l15;
    if (quad == 0) {          // head cols 0..3 = mean
      float4 mb = *(const float4*)meanb;
      float4 o;
      o.x = a4[0] + mb.x; o.y = a4[1] + mb.y;
      o.z = a4[2] + mb.z; o.w = a4[3] + mb.w;
      *reinterpret_cast<float4*>(&out[(size_t)row * 4]) = o;
    } else if (quad == 1) {   // head cols 4..7 = logstd (clipped)
      float4 lb = *(const float4*)logstdb;
      float4 o;
      o.x = fminf(fmaxf(a4[0] + lb.x, -20.f), 2.f);
      o.y = fminf(fmaxf(a4[1] + lb.y, -20.f), 2.f);
      o.z = fminf(fmaxf(a4[2] + lb.z, -20.f), 2.f);
      o.w = fminf(fmaxf(a4[3] + lb.w, -20.f), 2.f);
      *reinterpret_cast<float4*>(&out[(size_t)B_TOTAL * 4 + (size_t)row * 4]) = o;
    }
  }
}

extern "C" void kernel_launch(void* const* d_in, const int* in_sizes, int n_in,
                              void* d_out, int out_size, void* d_ws, size_t ws_size,
                              hipStream_t stream) {
  const float* obs      = (const float*)d_in[0];
  const float* ag       = (const float*)d_in[1];
  const float* g        = (const float*)d_in[2];
  const float* phi_w1   = (const float*)d_in[3];
  const float* phi_b1   = (const float*)d_in[4];
  const float* phi_w2   = (const float*)d_in[5];
  const float* phi_b2   = (const float*)d_in[6];
  const float* rho_w1   = (const float*)d_in[7];
  const float* rho_b1   = (const float*)d_in[8];
  const float* mean_w   = (const float*)d_in[9];
  const float* mean_b   = (const float*)d_in[10];
  const float* logstd_w = (const float*)d_in[11];
  const float* logstd_b = (const float*)d_in[12];
  float* out = (float*)d_out;

  // ws (bf16): W1P 6x32768 | W2f 65536 | W3f 65536 | W4f 4096 elems
  char* ws = (char*)d_ws;
  __hip_bfloat16* W1P = (__hip_bfloat16*)(ws);
  __hip_bfloat16* W2f = (__hip_bfloat16*)(ws + 393216);
  __hip_bfloat16* W3f = (__hip_bfloat16*)(ws + 393216 + 131072);
  __hip_bfloat16* W4f = (__hip_bfloat16*)(ws + 393216 + 262144);

  prep_weights<<<162, 256, 0, stream>>>(phi_w1, phi_b1, phi_w2, rho_w1,
                                        mean_w, logstd_w, W1P, W2f, W3f, W4f);
  actor_main<<<B_TOTAL / TROWS, 512, 0, stream>>>(
      obs, ag, g, W1P, W2f, W3f, W4f, phi_b2, rho_b1, mean_b, logstd_b, out);
}